// Round 1
// baseline (66.240 us; speedup 1.0000x reference)
//
#include <hip/hip_runtime.h>
#include <cmath>

// VarRateResampler, ratio=2: per (b,t) two 21-tap FIRs with polyphase rows
// selected by an NCO. For step_inc s in [Q/2,Q] the NCO has closed form
// acc_t = ceil(t*Q/s)*s - t*Q  (invariant acc in [0,Q)), so indices are
// computed in parallel by a tiny prep kernel; main kernel is a pure FIR.

#define QQ   128      // polyphase bank rows
#define LT   21       // taps per sub-filter
#define TT   4096     // time length (fixed by problem)
#define TILE 1024     // time samples per block
#define BLK  256      // threads per block
#define HP   24       // padded row stride (floats) -> 96B, 16B-aligned rows

__global__ void prep_kernel(const float* __restrict__ hs,
                            const float* __restrict__ accp,
                            int*  __restrict__ nco,    // 2*TT ints: (idx0,idx1) per t
                            float* __restrict__ hpad)  // QQ*HP padded taps
{
    int t = blockIdx.x * blockDim.x + threadIdx.x;

    // pad taps table: 128*24 = 3072 entries (grid is 4096 threads)
    if (t < QQ * HP) {
        int r = t / HP, c = t - r * HP;
        hpad[t] = (c < LT) ? hs[r * LT + c] : 0.0f;
    }

    if (t < TT) {
        float sf = 64.0f + accp[0];               // step_inc (f32, like reference)
        double s = (double)sf;
        double m = ceil(((double)t * 128.0) / s); // outputs emitted before step t
        float a = (float)(m * s - (double)t * 128.0); // acc entering step t
        // replicate the per-step slot logic of the reference
        bool  v0   = a < 128.0f;
        float ind0 = v0 ? a : -1.0f;
        float a1   = v0 ? a + sf : a;
        bool  v1   = a1 < 128.0f;
        float ind1 = v1 ? a1 : -1.0f;
        int i0 = min((int)rintf(ind0), QQ - 1);   // -1 => invalid => NaN out
        int i1 = min((int)rintf(ind1), QQ - 1);
        nco[2 * t]     = i0;
        nco[2 * t + 1] = i1;
    }
}

__global__ __launch_bounds__(BLK) void fir_kernel(
    const float* __restrict__ x,
    const int*   __restrict__ nco,
    const float* __restrict__ hpad,
    float*       __restrict__ y)
{
    __shared__ float xs[TILE + 20];               // 1044 floats = 261 float4
    const int b   = blockIdx.y;
    const int t0  = blockIdx.x * TILE;
    const int tid = threadIdx.x;
    const size_t row = (size_t)b * TT;

    // ---- stage x[t0-20 .. t0+TILE-1] into LDS ----
    if (blockIdx.x != 0) {
        // (row + t0 - 20) % 4 == 0  -> 16B-aligned float4 path
        const float4* src = (const float4*)(x + row + t0 - 20);
        float4* dst = (float4*)xs;
        dst[tid] = src[tid];
        if (tid < 5) dst[BLK + tid] = src[BLK + tid];   // 261 quads total
    } else {
        for (int i = tid; i < TILE + 20; i += BLK) {
            int gt = i - 20;
            xs[i] = (gt >= 0) ? x[row + gt] : 0.0f;     // fifo zero-init
        }
    }
    __syncthreads();

    // ---- each thread: 4 consecutive outputs t = t0 + 4*tid + k ----
    const int tl = tid * 4;
    const float4* xq = (const float4*)xs;               // quad i = floats 4i..4i+3
    float4 q0 = xq[tid + 0], q1 = xq[tid + 1], q2 = xq[tid + 2],
           q3 = xq[tid + 3], q4 = xq[tid + 4], q5 = xq[tid + 5];
    float xr[24] = {q0.x,q0.y,q0.z,q0.w, q1.x,q1.y,q1.z,q1.w,
                    q2.x,q2.y,q2.z,q2.w, q3.x,q3.y,q3.z,q3.w,
                    q4.x,q4.y,q4.z,q4.w, q5.x,q5.y,q5.z,q5.w};

    const int tg = t0 + tl;                             // global t of k=0
    const int4* np = (const int4*)(nco + 2 * tg);       // 32B-aligned
    const int4 n01 = np[0];   // (i0 k0, i1 k0, i0 k1, i1 k1)
    const int4 n23 = np[1];   // (i0 k2, i1 k2, i0 k3, i1 k3)

    const float NaNf = __int_as_float(0x7fc00000);
    float out[8];

    #pragma unroll
    for (int k = 0; k < 4; ++k) {
        const int i0 = (k == 0) ? n01.x : (k == 1) ? n01.z : (k == 2) ? n23.x : n23.z;
        const int i1 = (k == 0) ? n01.y : (k == 1) ? n01.w : (k == 2) ? n23.y : n23.w;
        const int r0 = (i0 < 0) ? 0 : i0;
        const int r1 = (i1 < 0) ? 0 : i1;

        // taps row 0 (uniform address across lanes in practice -> L1 broadcast)
        {
            const float4* hp = (const float4*)(hpad + r0 * HP);
            float4 ha = hp[0], hb = hp[1], hc = hp[2], hd = hp[3], he = hp[4], hf = hp[5];
            float h[24] = {ha.x,ha.y,ha.z,ha.w, hb.x,hb.y,hb.z,hb.w,
                           hc.x,hc.y,hc.z,hc.w, hd.x,hd.y,hd.z,hd.w,
                           he.x,he.y,he.z,he.w, hf.x,hf.y,hf.z,hf.w};
            float acc = 0.0f;
            #pragma unroll
            for (int l = 0; l < LT; ++l) acc = fmaf(h[l], xr[k + l], acc);
            out[2 * k] = (i0 < 0) ? NaNf : acc;
        }
        // taps row 1
        {
            const float4* hp = (const float4*)(hpad + r1 * HP);
            float4 ha = hp[0], hb = hp[1], hc = hp[2], hd = hp[3], he = hp[4], hf = hp[5];
            float h[24] = {ha.x,ha.y,ha.z,ha.w, hb.x,hb.y,hb.z,hb.w,
                           hc.x,hc.y,hc.z,hc.w, hd.x,hd.y,hd.z,hd.w,
                           he.x,he.y,he.z,he.w, hf.x,hf.y,hf.z,hf.w};
            float acc = 0.0f;
            #pragma unroll
            for (int l = 0; l < LT; ++l) acc = fmaf(h[l], xr[k + l], acc);
            out[2 * k + 1] = (i1 < 0) ? NaNf : acc;
        }
    }

    // ---- write (B, T, 2): 8 floats = 2 float4, 32B-aligned ----
    float4* yq = (float4*)(y + (row + (size_t)tg) * 2);
    yq[0] = make_float4(out[0], out[1], out[2], out[3]);
    yq[1] = make_float4(out[4], out[5], out[6], out[7]);
}

extern "C" void kernel_launch(void* const* d_in, const int* in_sizes, int n_in,
                              void* d_out, int out_size, void* d_ws, size_t ws_size,
                              hipStream_t stream) {
    const float* x    = (const float*)d_in[0];   // (B, 4096) f32
    const float* hs   = (const float*)d_in[1];   // (128, 21) f32
    const float* accp = (const float*)d_in[2];   // scalar f32
    float* y = (float*)d_out;                    // (B, 4096, 2) f32

    const int B = in_sizes[0] / TT;

    int*   nco  = (int*)d_ws;                                   // 2*TT ints = 32 KB
    float* hpad = (float*)((char*)d_ws + 2 * TT * sizeof(int)); // 128*24 f32 = 12 KB

    prep_kernel<<<TT / 256, 256, 0, stream>>>(hs, accp, nco, hpad);

    dim3 grid(TT / TILE, B);
    fir_kernel<<<grid, BLK, 0, stream>>>(x, nco, hpad, y);
}

// Round 3
// 35.179 us; speedup vs baseline: 1.8830x; 1.8830x over previous
//
#include <hip/hip_runtime.h>
#include <cmath>

// VarRateResampler, ratio=2: per (b,t) two 21-tap FIRs with polyphase rows
// selected by an NCO. NCO has closed form acc_t = ceil(t*Q/s)*s - t*Q for
// s in [Q/2,Q], so indices are computed in parallel by a tiny prep kernel.
// fir_kernel: wave detects that tap-row indices are uniform (true for
// ratio=2.0) and loads the two rows through the SCALAR path (s_load into
// SGPRs, once per wave) instead of 48 per-lane vector loads -> removes the
// L1 bandwidth bottleneck seen in round 1 (19% VALUBusy, 15% HBM).

#define QQ   128      // polyphase bank rows
#define LT   21       // taps per sub-filter
#define TT   4096     // time length (fixed by problem)
#define TILE 1024     // time samples per block
#define BLK  256      // threads per block
#define HP   24       // padded row stride (floats) -> 96B, 16B-aligned rows

typedef float float4n __attribute__((ext_vector_type(4)));   // native vec for nontemporal

__global__ void prep_kernel(const float* __restrict__ hs,
                            const float* __restrict__ accp,
                            int*  __restrict__ nco,    // 2*TT ints: (idx0,idx1) per t
                            float* __restrict__ hpad)  // QQ*HP padded taps
{
    int t = blockIdx.x * blockDim.x + threadIdx.x;

    if (t < QQ * HP) {
        int r = t / HP, c = t - r * HP;
        hpad[t] = (c < LT) ? hs[r * LT + c] : 0.0f;
    }

    if (t < TT) {
        float sf = 64.0f + accp[0];               // step_inc (f32, like reference)
        double s = (double)sf;
        double m = ceil(((double)t * 128.0) / s); // outputs emitted before step t
        float a = (float)(m * s - (double)t * 128.0); // acc entering step t
        bool  v0   = a < 128.0f;
        float ind0 = v0 ? a : -1.0f;
        float a1   = v0 ? a + sf : a;
        bool  v1   = a1 < 128.0f;
        float ind1 = v1 ? a1 : -1.0f;
        int i0 = min((int)rintf(ind0), QQ - 1);   // -1 => invalid => NaN out
        int i1 = min((int)rintf(ind1), QQ - 1);
        nco[2 * t]     = i0;
        nco[2 * t + 1] = i1;
    }
}

__global__ __launch_bounds__(BLK) void fir_kernel(
    const float* __restrict__ x,
    const int*   __restrict__ nco,
    const float* __restrict__ hpad,
    float*       __restrict__ y)
{
    __shared__ float xs[TILE + 20];               // 1044 floats = 261 float4
    const int b   = blockIdx.y;
    const int t0  = blockIdx.x * TILE;
    const int tid = threadIdx.x;
    const size_t row = (size_t)b * TT;

    // ---- issue nco load early (latency hides under x staging + barrier) ----
    const int tl = tid * 4;
    const int tg = t0 + tl;                             // global t of k=0
    const int4* np = (const int4*)(nco + 2 * tg);       // 32B-aligned
    const int4 n01 = np[0];   // (i0 k0, i1 k0, i0 k1, i1 k1)
    const int4 n23 = np[1];   // (i0 k2, i1 k2, i0 k3, i1 k3)

    // ---- stage x[t0-20 .. t0+TILE-1] into LDS ----
    if (blockIdx.x != 0) {
        // (row + t0 - 20) % 4 == 0  -> 16B-aligned float4 path
        const float4* src = (const float4*)(x + row + t0 - 20);
        float4* dst = (float4*)xs;
        dst[tid] = src[tid];
        if (tid < 5) dst[BLK + tid] = src[BLK + tid];   // 261 quads total
    } else {
        for (int i = tid; i < TILE + 20; i += BLK) {
            int gt = i - 20;
            xs[i] = (gt >= 0) ? x[row + gt] : 0.0f;     // fifo zero-init
        }
    }
    __syncthreads();

    // ---- each thread: 4 consecutive outputs t = tg + k ----
    const float4* xq = (const float4*)xs;               // quad i = floats 4i..4i+3
    float4 q0 = xq[tid + 0], q1 = xq[tid + 1], q2 = xq[tid + 2],
           q3 = xq[tid + 3], q4 = xq[tid + 4], q5 = xq[tid + 5];
    float xr[24] = {q0.x,q0.y,q0.z,q0.w, q1.x,q1.y,q1.z,q1.w,
                    q2.x,q2.y,q2.z,q2.w, q3.x,q3.y,q3.z,q3.w,
                    q4.x,q4.y,q4.z,q4.w, q5.x,q5.y,q5.z,q5.w};

    float out[8];

    // ---- wave-uniform fast path: same two tap rows for all lanes & slots ----
    const int f0 = __builtin_amdgcn_readfirstlane(n01.x);
    const int f1 = __builtin_amdgcn_readfirstlane(n01.y);
    const bool kuni = (n01.x == n01.z) & (n01.x == n23.x) & (n01.x == n23.z) &
                      (n01.y == n01.w) & (n01.y == n23.y) & (n01.y == n23.w);
    const bool luni = (n01.x == f0) & (n01.y == f1);

    if (__all(kuni & luni) && f0 >= 0 && f1 >= 0) {
        // taps addresses are wave-uniform -> scalar loads into SGPRs, once.
        const float* __restrict__ h0 = hpad + (size_t)f0 * HP;
        const float* __restrict__ h1 = hpad + (size_t)f1 * HP;
        #pragma unroll
        for (int k = 0; k < 4; ++k) {
            float a0 = 0.0f, a1 = 0.0f;
            #pragma unroll
            for (int l = 0; l < LT; ++l) {
                a0 = fmaf(h0[l], xr[k + l], a0);
                a1 = fmaf(h1[l], xr[k + l], a1);
            }
            out[2 * k]     = a0;
            out[2 * k + 1] = a1;
        }
    } else {
        // ---- generic per-lane gather path (any acc_phase) ----
        const float NaNf = __int_as_float(0x7fc00000);
        #pragma unroll
        for (int k = 0; k < 4; ++k) {
            const int i0 = (k == 0) ? n01.x : (k == 1) ? n01.z : (k == 2) ? n23.x : n23.z;
            const int i1 = (k == 0) ? n01.y : (k == 1) ? n01.w : (k == 2) ? n23.y : n23.w;
            const int r0 = (i0 < 0) ? 0 : i0;
            const int r1 = (i1 < 0) ? 0 : i1;
            {
                const float4* hp = (const float4*)(hpad + r0 * HP);
                float4 ha = hp[0], hb = hp[1], hc = hp[2], hd = hp[3], he = hp[4], hf = hp[5];
                float h[24] = {ha.x,ha.y,ha.z,ha.w, hb.x,hb.y,hb.z,hb.w,
                               hc.x,hc.y,hc.z,hc.w, hd.x,hd.y,hd.z,hd.w,
                               he.x,he.y,he.z,he.w, hf.x,hf.y,hf.z,hf.w};
                float acc = 0.0f;
                #pragma unroll
                for (int l = 0; l < LT; ++l) acc = fmaf(h[l], xr[k + l], acc);
                out[2 * k] = (i0 < 0) ? NaNf : acc;
            }
            {
                const float4* hp = (const float4*)(hpad + r1 * HP);
                float4 ha = hp[0], hb = hp[1], hc = hp[2], hd = hp[3], he = hp[4], hf = hp[5];
                float h[24] = {ha.x,ha.y,ha.z,ha.w, hb.x,hb.y,hb.z,hb.w,
                               hc.x,hc.y,hc.z,hc.w, hd.x,hd.y,hd.z,hd.w,
                               he.x,he.y,he.z,he.w, hf.x,hf.y,hf.z,hf.w};
                float acc = 0.0f;
                #pragma unroll
                for (int l = 0; l < LT; ++l) acc = fmaf(h[l], xr[k + l], acc);
                out[2 * k + 1] = (i1 < 0) ? NaNf : acc;
            }
        }
    }

    // ---- write (B, T, 2): 8 floats = 2 float4, nontemporal stream ----
    float4n* yq = (float4n*)(y + (row + (size_t)tg) * 2);
    float4n o0 = {out[0], out[1], out[2], out[3]};
    float4n o1 = {out[4], out[5], out[6], out[7]};
    __builtin_nontemporal_store(o0, yq + 0);
    __builtin_nontemporal_store(o1, yq + 1);
}

extern "C" void kernel_launch(void* const* d_in, const int* in_sizes, int n_in,
                              void* d_out, int out_size, void* d_ws, size_t ws_size,
                              hipStream_t stream) {
    const float* x    = (const float*)d_in[0];   // (B, 4096) f32
    const float* hs   = (const float*)d_in[1];   // (128, 21) f32
    const float* accp = (const float*)d_in[2];   // scalar f32
    float* y = (float*)d_out;                    // (B, 4096, 2) f32

    const int B = in_sizes[0] / TT;

    int*   nco  = (int*)d_ws;                                   // 2*TT ints = 32 KB
    float* hpad = (float*)((char*)d_ws + 2 * TT * sizeof(int)); // 128*24 f32 = 12 KB

    prep_kernel<<<TT / 256, 256, 0, stream>>>(hs, accp, nco, hpad);

    dim3 grid(TT / TILE, B);
    fir_kernel<<<grid, BLK, 0, stream>>>(x, nco, hpad, y);
}